// Round 13
// baseline (1085.599 us; speedup 1.0000x reference)
//
#include <hip/hip_runtime.h>

// SignNet GINE: 3 layers, signs batched as 2N interleaved rows (2i=+x, 2i+1=-x).
// CSR gather aggregation (agg128 = proven r8/r12). Layers 1-2 node MLP split
// into MFMA kernels: mlp_a (X+AGG)@W1->relu->Hhi/Hlo bf16 planes, and
// mlp_b H@W2->OUT, with hi/lo-split operands (r7-verified numerics).
constexpr int DHID = 128;

typedef __attribute__((ext_vector_type(8))) short bf16x8v;
typedef __attribute__((ext_vector_type(4))) float f32x4v;

__device__ __forceinline__ float b2f(unsigned short u) {
    union { unsigned int i; float f; } v;
    v.i = ((unsigned int)u) << 16;
    return v.f;
}
__device__ __forceinline__ unsigned short f2b(float f) {
    union { float f; unsigned int i; } v;
    v.f = f;
    unsigned int x = v.i;
    return (unsigned short)((x + 0x7fff + ((x >> 16) & 1)) >> 16);
}
__device__ __forceinline__ unsigned int pack2(float a, float b) {
    return (unsigned int)f2b(a) | ((unsigned int)f2b(b) << 16);
}
__device__ __forceinline__ float bres(float w) { return w - b2f(f2b(w)); }
__device__ __forceinline__ void dot2b(float& acc, unsigned int a, unsigned int b) {
    asm("v_dot2_f32_bf16 %0, %1, %2, %0" : "+v"(acc) : "v"(a), "v"(b));
}

__global__ __launch_bounds__(256)
void init_h0(const float* __restrict__ x, float* __restrict__ H0,
             unsigned short* __restrict__ H0B, int n) {
    int i = blockIdx.x * 256 + threadIdx.x;   // over N*16
    if (i < n * 16) {
        int r = i >> 4, c = i & 15;
        float v = x[i];
        H0[(size_t)(2 * r) * 16 + c] = v;
        H0[(size_t)(2 * r + 1) * 16 + c] = -v;
        H0B[(size_t)(2 * r) * 16 + c] = f2b(v);
        H0B[(size_t)(2 * r + 1) * 16 + c] = f2b(-v);
    }
}

__global__ __launch_bounds__(256)
void sum_signs(const float* __restrict__ H3, float* __restrict__ S, int n) {
    int i = blockIdx.x * 256 + threadIdx.x;   // over N*64
    if (i < n * 64) {
        int r = i >> 6;
        S[i] = H3[i + (size_t)r * 64] + H3[i + (size_t)r * 64 + 64];
    }
}

// ---------------- CSR build ----------------
__global__ __launch_bounds__(256)
void csr_count(const int* __restrict__ DST, int* __restrict__ deg, int E_) {
    int e = blockIdx.x * 256 + threadIdx.x;
    if (e < E_) atomicAdd(&deg[DST[e]], 1);
}

__global__ __launch_bounds__(256)
void scan1(const int* __restrict__ deg, int* __restrict__ off,
           int* __restrict__ bsum, int n) {
    __shared__ int s[256];
    int tid = threadIdx.x;
    int i = blockIdx.x * 256 + tid;
    int v = (i < n) ? deg[i] : 0;
    s[tid] = v;
    __syncthreads();
    for (int d = 1; d < 256; d <<= 1) {
        int t = (tid >= d) ? s[tid - d] : 0;
        __syncthreads();
        if (tid >= d) s[tid] += t;
        __syncthreads();
    }
    if (i < n) off[i] = s[tid] - v;
    if (tid == 255) bsum[blockIdx.x] = s[255];
}

__global__ __launch_bounds__(256)
void scan2(int* __restrict__ bsum, int nb) {
    __shared__ int s[256];
    int tid = threadIdx.x;
    int v = (tid < nb) ? bsum[tid] : 0;
    s[tid] = v;
    __syncthreads();
    for (int d = 1; d < 256; d <<= 1) {
        int t = (tid >= d) ? s[tid - d] : 0;
        __syncthreads();
        if (tid >= d) s[tid] += t;
        __syncthreads();
    }
    if (tid < nb) bsum[tid] = s[tid] - v;
}

__global__ __launch_bounds__(256)
void scan3(int* __restrict__ off, int* __restrict__ pos,
           const int* __restrict__ bsum, const int* __restrict__ deg, int n) {
    int i = blockIdx.x * 256 + threadIdx.x;
    if (i < n) {
        int o = off[i] + bsum[blockIdx.x];
        off[i] = o;
        pos[i] = o;
        if (i == n - 1) off[n] = o + deg[i];
    }
}

// Fill CSR: src index + edge attrs gathered into CSR order as bf16 (32B/edge).
__global__ __launch_bounds__(256)
void csr_fill(const int* __restrict__ SRC, const int* __restrict__ DST,
              const float* __restrict__ EA, int* __restrict__ pos,
              int* __restrict__ csrsrc, uint4* __restrict__ EABS, int E_) {
    int e = blockIdx.x * 256 + threadIdx.x;
    if (e < E_) {
        int d = DST[e];
        int j = atomicAdd(&pos[d], 1);
        csrsrc[j] = SRC[e];
        const float4* ea4 = (const float4*)(EA + (size_t)e * 16);
        float4 q0 = ea4[0], q1 = ea4[1], q2 = ea4[2], q3 = ea4[3];
        uint4 o0, o1;
        o0.x = pack2(q0.x, q0.y); o0.y = pack2(q0.z, q0.w);
        o0.z = pack2(q1.x, q1.y); o0.w = pack2(q1.z, q1.w);
        o1.x = pack2(q2.x, q2.y); o1.y = pack2(q2.z, q2.w);
        o1.z = pack2(q3.x, q3.y); o1.w = pack2(q3.z, q3.w);
        EABS[(size_t)2 * j] = o0;
        EABS[(size_t)2 * j + 1] = o1;
    }
}

// ---------------- gather aggregation (r12/r8 proven) ----------------
__global__ __launch_bounds__(256)
void agg_gather128(const int* __restrict__ CSRS, const int* __restrict__ OFF,
                   const unsigned short* __restrict__ EABS,
                   const float* __restrict__ WE, const float* __restrict__ BE,
                   const unsigned short* __restrict__ HB,
                   float* __restrict__ AGG, int n) {
    __shared__ float esm_all[4][16][132];
    const int tid = threadIdx.x;
    const int wv = tid >> 6;
    const int lane = tid & 63;
    const int node = blockIdx.x * 4 + wv;
    if (node >= n) return;
    float (*esm)[132] = esm_all[wv];

    const int col = lane & 15;
    const int grp = lane >> 4;          // 0..3
    const int klo = (grp & 1) * 8;

    bf16x8v bfrag[8];
#pragma unroll
    for (int cb = 0; cb < 8; ++cb) {
        bf16x8v b;
#pragma unroll
        for (int i = 0; i < 8; ++i) {
            float w = WE[(klo + i) * 128 + cb * 16 + col];
            unsigned short hi = f2b(w);
            unsigned short lo = f2b(bres(w));
            b[i] = (short)(grp >= 2 ? lo : hi);
        }
        bfrag[cb] = b;
    }
    float bias[8];
#pragma unroll
    for (int cb = 0; cb < 8; ++cb) bias[cb] = BE[cb * 16 + col];

    const int o = lane & 31;
    const int s = o >> 4;
    const int co = (o & 15) * 8;
    const int ep = lane >> 5;

    float acc[8];
#pragma unroll
    for (int i = 0; i < 8; ++i) acc[i] = 0.f;

    const int j0 = OFF[node], j1 = OFF[node + 1];
    const char* ebase = (const char*)EABS;

    for (int base = j0; base < j1; base += 16) {
        const int rem = j1 - base;
        uint4 a4 = *(const uint4*)(ebase + ((size_t)(base + col) << 5) +
                                   ((grp & 1) << 4));
        bf16x8v afrag = __builtin_bit_cast(bf16x8v, a4);
#pragma unroll
        for (int cb = 0; cb < 8; ++cb) {
            f32x4v c = {bias[cb], bias[cb], bias[cb], bias[cb]};
            f32x4v ev = __builtin_amdgcn_mfma_f32_16x16x32_bf16(afrag, bfrag[cb],
                                                                c, 0, 0, 0);
#pragma unroll
            for (int r = 0; r < 4; ++r) {
                const int slot = grp * 4 + r;
                esm[slot][cb * 16 + col] = (slot < rem) ? ev[r] : -1e30f;
            }
        }
        int srcs[8];
#pragma unroll
        for (int i = 0; i < 8; ++i) {
            const int eidx = base + 2 * i + ep;
            srcs[i] = CSRS[eidx < j1 ? eidx : (j1 - 1)];
        }
        uint4 hvv[8];
#pragma unroll
        for (int i = 0; i < 8; ++i)
            hvv[i] = *(const uint4*)(HB + (((size_t)(2 * srcs[i] + s)) << 7) + co);
#pragma unroll
        for (int i = 0; i < 8; ++i) {
            const uint4 hv = hvv[i];
            const float4* ep4 = (const float4*)&esm[2 * i + ep][co];
            float4 e0 = ep4[0], e1 = ep4[1];
            acc[0] += fmaxf(b2f(hv.x & 0xffff) + e0.x, 0.f);
            acc[1] += fmaxf(b2f(hv.x >> 16)    + e0.y, 0.f);
            acc[2] += fmaxf(b2f(hv.y & 0xffff) + e0.z, 0.f);
            acc[3] += fmaxf(b2f(hv.y >> 16)    + e0.w, 0.f);
            acc[4] += fmaxf(b2f(hv.z & 0xffff) + e1.x, 0.f);
            acc[5] += fmaxf(b2f(hv.z >> 16)    + e1.y, 0.f);
            acc[6] += fmaxf(b2f(hv.w & 0xffff) + e1.z, 0.f);
            acc[7] += fmaxf(b2f(hv.w >> 16)    + e1.w, 0.f);
        }
    }
#pragma unroll
    for (int i = 0; i < 8; ++i) acc[i] += __shfl_xor(acc[i], 32);
    if (lane < 32) {
        float* arow = AGG + (size_t)(2 * node + s) * 128 + co;
        float4 v0 = make_float4(acc[0], acc[1], acc[2], acc[3]);
        float4 v1 = make_float4(acc[4], acc[5], acc[6], acc[7]);
        ((float4*)arow)[0] = v0;
        ((float4*)arow)[1] = v1;
    }
}

// din=16: half-wave (32 lanes) per node.
__global__ __launch_bounds__(256)
void agg_gather16(const int* __restrict__ CSRS, const int* __restrict__ OFF,
                  const uint4* __restrict__ EABS, const float* __restrict__ WE,
                  const float* __restrict__ BE,
                  const unsigned short* __restrict__ HB,
                  float* __restrict__ AGG, int n) {
    const int l = threadIdx.x & 31;
    const int node = blockIdx.x * 8 + (threadIdx.x >> 5);
    if (node >= n) return;
    const int s = l >> 4;
    const int c = l & 15;
    unsigned int wh[8], wl[8];
#pragma unroll
    for (int t = 0; t < 8; ++t) {
        float a0 = WE[(2 * t) * 16 + c], a1 = WE[(2 * t + 1) * 16 + c];
        wh[t] = pack2(a0, a1);
        wl[t] = pack2(bres(a0), bres(a1));
    }
    const float bev = BE[c];
    float acc = 0.f;
    const int j0 = OFF[node], j1 = OFF[node + 1];
#pragma unroll 4
    for (int j = j0; j < j1; ++j) {
        int src = CSRS[j];
        uint4 p = EABS[(size_t)2 * j], q = EABS[(size_t)2 * j + 1];
        float ec = bev;
        dot2b(ec, p.x, wh[0]); dot2b(ec, p.y, wh[1]);
        dot2b(ec, p.z, wh[2]); dot2b(ec, p.w, wh[3]);
        dot2b(ec, q.x, wh[4]); dot2b(ec, q.y, wh[5]);
        dot2b(ec, q.z, wh[6]); dot2b(ec, q.w, wh[7]);
        dot2b(ec, p.x, wl[0]); dot2b(ec, p.y, wl[1]);
        dot2b(ec, p.z, wl[2]); dot2b(ec, p.w, wl[3]);
        dot2b(ec, q.x, wl[4]); dot2b(ec, q.y, wl[5]);
        dot2b(ec, q.z, wl[6]); dot2b(ec, q.w, wl[7]);
        float hv = b2f(HB[(size_t)(2 * src + s) * 16 + c]);
        acc += fmaxf(hv + ec, 0.f);
    }
    AGG[(size_t)(2 * node + s) * 16 + c] = acc;
}

// ---------------- MFMA node MLP, split (layers 1-2) ----------------
// mlp_a: hidden = relu((X+AGG)@W1 + b1) -> Hhi/Hlo bf16 planes. DIN=128.
// Block 256 = 4 waves, 128 rows; wave owns 2 col-blocks (32 cols).
// Precision (r7-verified): B = [Whi|Wlo] K-halves; A1=[Xhi|Xhi], A2=[Xlo|0].
__global__ __launch_bounds__(256)
void mlp_a(const float* __restrict__ X, const float* __restrict__ AGG,
           const float* __restrict__ W1, const float* __restrict__ B1,
           unsigned short* __restrict__ Hhi, unsigned short* __restrict__ Hlo,
           int rows) {
    __shared__ unsigned short sHi[16][136];   // padded: row=272B, 16B-aligned
    __shared__ unsigned short sLo[16][136];
    const int tid = threadIdx.x;
    const int w = tid >> 6;
    const int lane = tid & 63;
    const int col = lane & 15;
    const int grp = lane >> 4;
    const int klo8 = (grp & 1) * 8;
    const bool hi_lane = grp < 2;
    const int row0 = blockIdx.x * 128;

    // W1 fragments (once per block, amortized over 128 rows)
    bf16x8v b1f[2][8];
    float bias1[2];
#pragma unroll
    for (int cb = 0; cb < 2; ++cb) {
        const int cbg = 2 * w + cb;
#pragma unroll
        for (int kc = 0; kc < 8; ++kc) {
            bf16x8v b;
#pragma unroll
            for (int i = 0; i < 8; ++i) {
                float wv = W1[(size_t)(kc * 16 + klo8 + i) * 128 + cbg * 16 + col];
                b[i] = (short)(hi_lane ? f2b(wv) : f2b(bres(wv)));
            }
            b1f[cb][kc] = b;
        }
        bias1[cb] = B1[cbg * 16 + col];
    }

    for (int rg = 0; rg < 8; ++rg) {
        __syncthreads();   // previous rg's sHi/sLo reads done
        {   // stage 16 rows x 128 k as bf16 hi/lo
            const int r = tid >> 4;
            const int kb = (tid & 15) * 8;
            const int gr = row0 + rg * 16 + r;
            float v[8];
            if (gr < rows) {
                const float4* xp = (const float4*)(X + (size_t)gr * 128 + kb);
                const float4* ap = (const float4*)(AGG + (size_t)gr * 128 + kb);
                float4 x0 = xp[0], x1 = xp[1], g0 = ap[0], g1 = ap[1];
                v[0] = x0.x + g0.x; v[1] = x0.y + g0.y;
                v[2] = x0.z + g0.z; v[3] = x0.w + g0.w;
                v[4] = x1.x + g1.x; v[5] = x1.y + g1.y;
                v[6] = x1.z + g1.z; v[7] = x1.w + g1.w;
            } else {
#pragma unroll
                for (int i = 0; i < 8; ++i) v[i] = 0.f;
            }
            uint4 ph, pl;
            ph.x = pack2(v[0], v[1]); ph.y = pack2(v[2], v[3]);
            ph.z = pack2(v[4], v[5]); ph.w = pack2(v[6], v[7]);
            pl.x = pack2(bres(v[0]), bres(v[1])); pl.y = pack2(bres(v[2]), bres(v[3]));
            pl.z = pack2(bres(v[4]), bres(v[5])); pl.w = pack2(bres(v[6]), bres(v[7]));
            *(uint4*)&sHi[r][kb] = ph;
            *(uint4*)&sLo[r][kb] = pl;
        }
        __syncthreads();
        f32x4v acc0 = {bias1[0], bias1[0], bias1[0], bias1[0]};
        f32x4v acc1 = {bias1[1], bias1[1], bias1[1], bias1[1]};
#pragma unroll
        for (int kc = 0; kc < 8; ++kc) {
            bf16x8v a1 = *(const bf16x8v*)&sHi[col][kc * 16 + klo8];
            bf16x8v a2;
            if (hi_lane) {
                a2 = *(const bf16x8v*)&sLo[col][kc * 16 + klo8];
            } else {
#pragma unroll
                for (int i = 0; i < 8; ++i) a2[i] = 0;
            }
            acc0 = __builtin_amdgcn_mfma_f32_16x16x32_bf16(a1, b1f[0][kc], acc0, 0, 0, 0);
            acc0 = __builtin_amdgcn_mfma_f32_16x16x32_bf16(a2, b1f[0][kc], acc0, 0, 0, 0);
            acc1 = __builtin_amdgcn_mfma_f32_16x16x32_bf16(a1, b1f[1][kc], acc1, 0, 0, 0);
            acc1 = __builtin_amdgcn_mfma_f32_16x16x32_bf16(a2, b1f[1][kc], acc1, 0, 0, 0);
        }
#pragma unroll
        for (int cb = 0; cb < 2; ++cb) {
            const f32x4v acc = cb ? acc1 : acc0;
            const int cbg = 2 * w + cb;
#pragma unroll
            for (int r = 0; r < 4; ++r) {
                const int gr = row0 + rg * 16 + grp * 4 + r;
                if (gr < rows) {
                    float vv = fmaxf(acc[r], 0.f);
                    unsigned short h = f2b(vv);
                    Hhi[(size_t)gr * 128 + cbg * 16 + col] = h;
                    Hlo[(size_t)gr * 128 + cbg * 16 + col] = f2b(bres(vv));
                }
            }
        }
    }
}

// mlp_b: OUT = maybe_relu(H @ W2 + b2); H read as bf16 hi/lo planes (b128).
template <int DOUT, bool RELU_OUT, bool WRITE_B>
__global__ __launch_bounds__(256)
void mlp_b(const unsigned short* __restrict__ Hhi,
           const unsigned short* __restrict__ Hlo,
           const float* __restrict__ W2, const float* __restrict__ B2,
           float* __restrict__ OUT, unsigned short* __restrict__ OUTB, int rows) {
    constexpr int NB = DOUT / 16;        // 8 or 4
    constexpr int CBW = NB / 4;          // 2 or 1 col-blocks per wave
    const int tid = threadIdx.x;
    const int w = tid >> 6;
    const int lane = tid & 63;
    const int col = lane & 15;
    const int grp = lane >> 4;
    const int klo8 = (grp & 1) * 8;
    const bool hi_lane = grp < 2;
    const int row0 = blockIdx.x * 128;

    bf16x8v b2f0[8], b2f1[8];
    float bias2[2];
#pragma unroll
    for (int cb = 0; cb < CBW; ++cb) {
        const int cbg = w * CBW + cb;
#pragma unroll
        for (int kc = 0; kc < 8; ++kc) {
            bf16x8v b;
#pragma unroll
            for (int i = 0; i < 8; ++i) {
                float wv = W2[(size_t)(kc * 16 + klo8 + i) * DOUT + cbg * 16 + col];
                b[i] = (short)(hi_lane ? f2b(wv) : f2b(bres(wv)));
            }
            if (cb == 0) b2f0[kc] = b; else b2f1[kc] = b;
        }
        bias2[cb] = B2[cbg * 16 + col];
    }

    for (int rg = 0; rg < 8; ++rg) {
        int arow = row0 + rg * 16 + col;
        if (arow >= rows) arow = rows - 1;   // clamp (writes masked below)
        const unsigned short* hp = Hhi + (size_t)arow * 128;
        const unsigned short* lp = Hlo + (size_t)arow * 128;
        bf16x8v a1[8], a2[8];
#pragma unroll
        for (int kc = 0; kc < 8; ++kc) {
            a1[kc] = *(const bf16x8v*)(hp + kc * 16 + klo8);
            if (hi_lane) {
                a2[kc] = *(const bf16x8v*)(lp + kc * 16 + klo8);
            } else {
#pragma unroll
                for (int i = 0; i < 8; ++i) a2[kc][i] = 0;
            }
        }
        f32x4v acc0 = {bias2[0], bias2[0], bias2[0], bias2[0]};
        f32x4v acc1 = {bias2[1], bias2[1], bias2[1], bias2[1]};
#pragma unroll
        for (int kc = 0; kc < 8; ++kc) {
            acc0 = __builtin_amdgcn_mfma_f32_16x16x32_bf16(a1[kc], b2f0[kc], acc0, 0, 0, 0);
            acc0 = __builtin_amdgcn_mfma_f32_16x16x32_bf16(a2[kc], b2f0[kc], acc0, 0, 0, 0);
            if (CBW == 2) {
                acc1 = __builtin_amdgcn_mfma_f32_16x16x32_bf16(a1[kc], b2f1[kc], acc1, 0, 0, 0);
                acc1 = __builtin_amdgcn_mfma_f32_16x16x32_bf16(a2[kc], b2f1[kc], acc1, 0, 0, 0);
            }
        }
#pragma unroll
        for (int cb = 0; cb < CBW; ++cb) {
            const f32x4v acc = cb ? acc1 : acc0;
            const int cbg = w * CBW + cb;
#pragma unroll
            for (int r = 0; r < 4; ++r) {
                const int gr = row0 + rg * 16 + grp * 4 + r;
                if (gr < rows) {
                    float o = acc[r];
                    if (RELU_OUT) o = fmaxf(o, 0.f);
                    OUT[(size_t)gr * DOUT + cbg * 16 + col] = o;
                    if (WRITE_B)
                        OUTB[(size_t)gr * DOUT + cbg * 16 + col] = f2b(o);
                }
            }
        }
    }
}

// Fused node MLP (VALU, proven r5) — layer 0 and readout.
template <int DIN, int DOUT, bool RELU_OUT, bool HAS_AGG, bool WRITE_B>
__global__ __launch_bounds__(256)
void node_mlp(const float* __restrict__ X, const float* __restrict__ AGG,
              const float* __restrict__ W1, const float* __restrict__ B1,
              const float* __restrict__ W2, const float* __restrict__ B2,
              float* __restrict__ OUT, unsigned short* __restrict__ OUTB,
              int rows) {
    __shared__ float sX[32 * DIN];
    __shared__ float sH[32 * DHID];
    const int tid = threadIdx.x;

    for (int row0 = blockIdx.x * 32; row0 < rows; row0 += gridDim.x * 32) {
        __syncthreads();
        constexpr int DIN4 = DIN / 4;
        for (int i = tid; i < 32 * DIN4; i += 256) {
            int r = i / DIN4, k4 = i % DIN4;
            int gr = row0 + r;
            float4 v = make_float4(0.f, 0.f, 0.f, 0.f);
            if (gr < rows) {
                v = ((const float4*)X)[(size_t)gr * DIN4 + k4];
                if (HAS_AGG) {
                    float4 a = ((const float4*)AGG)[(size_t)gr * DIN4 + k4];
                    v.x += a.x; v.y += a.y; v.z += a.z; v.w += a.w;
                }
            }
            ((float4*)sX)[i] = v;
        }
        __syncthreads();
        {
            const int c = tid & 63;
            const int r0 = tid >> 6;
            float acc[8][2];
            const float b1a = B1[c], b1b = B1[c + 64];
#pragma unroll
            for (int j = 0; j < 8; ++j) {
                acc[j][0] = b1a;
                acc[j][1] = b1b;
            }
#pragma unroll 2
            for (int k4 = 0; k4 < DIN / 4; ++k4) {
                const int k = 4 * k4;
                float wa[4], wb[4];
#pragma unroll
                for (int kk = 0; kk < 4; ++kk) {
                    wa[kk] = W1[(k + kk) * DHID + c];
                    wb[kk] = W1[(k + kk) * DHID + c + 64];
                }
#pragma unroll
                for (int j = 0; j < 8; ++j) {
                    float4 xv = ((const float4*)sX)[((r0 + 4 * j) * DIN + k) >> 2];
                    acc[j][0] += xv.x * wa[0]; acc[j][1] += xv.x * wb[0];
                    acc[j][0] += xv.y * wa[1]; acc[j][1] += xv.y * wb[1];
                    acc[j][0] += xv.z * wa[2]; acc[j][1] += xv.z * wb[2];
                    acc[j][0] += xv.w * wa[3]; acc[j][1] += xv.w * wb[3];
                }
            }
#pragma unroll
            for (int j = 0; j < 8; ++j) {
                int r = r0 + 4 * j;
                sH[r * DHID + c] = fmaxf(acc[j][0], 0.f);
                sH[r * DHID + c + 64] = fmaxf(acc[j][1], 0.f);
            }
        }
        __syncthreads();
        {
            constexpr int HALF = DOUT / 2;
            constexpr int RP = 256 / HALF;
            constexpr int ITER = 32 / RP;
            const int c = tid % HALF;
            const int r0 = tid / HALF;
            float acc[ITER][2];
            const float bz0 = B2[c], bz1 = B2[c + HALF];
#pragma unroll
            for (int j = 0; j < ITER; ++j) {
                acc[j][0] = bz0;
                acc[j][1] = bz1;
            }
#pragma unroll 2
            for (int k4 = 0; k4 < DHID / 4; ++k4) {
                const int k = 4 * k4;
                float wa[4], wb[4];
#pragma unroll
                for (int kk = 0; kk < 4; ++kk) {
                    wa[kk] = W2[(k + kk) * DOUT + c];
                    wb[kk] = W2[(k + kk) * DOUT + c + HALF];
                }
#pragma unroll
                for (int j = 0; j < ITER; ++j) {
                    float4 hv = ((const float4*)sH)[((r0 + RP * j) * DHID + k) >> 2];
                    acc[j][0] += hv.x * wa[0]; acc[j][1] += hv.x * wb[0];
                    acc[j][0] += hv.y * wa[1]; acc[j][1] += hv.y * wb[1];
                    acc[j][0] += hv.z * wa[2]; acc[j][1] += hv.z * wb[2];
                    acc[j][0] += hv.w * wa[3]; acc[j][1] += hv.w * wb[3];
                }
            }
#pragma unroll
            for (int j = 0; j < ITER; ++j) {
                int gr = row0 + r0 + RP * j;
                if (gr < rows) {
                    float o0 = acc[j][0], o1 = acc[j][1];
                    if (RELU_OUT) {
                        o0 = fmaxf(o0, 0.f);
                        o1 = fmaxf(o1, 0.f);
                    }
                    OUT[(size_t)gr * DOUT + c] = o0;
                    OUT[(size_t)gr * DOUT + c + HALF] = o1;
                    if (WRITE_B) {
                        OUTB[(size_t)gr * DOUT + c] = f2b(o0);
                        OUTB[(size_t)gr * DOUT + c + HALF] = f2b(o1);
                    }
                }
            }
        }
    }
}

extern "C" void kernel_launch(void* const* d_in, const int* in_sizes, int n_in,
                              void* d_out, int out_size, void* d_ws, size_t ws_size,
                              hipStream_t stream) {
    const float* x = (const float*)d_in[0];
    const float* ea = (const float*)d_in[1];
    const int* esrc = (const int*)d_in[2];
    const int* edst = (const int*)d_in[3];
    const float* we0 = (const float*)d_in[4];
    const float* be0 = (const float*)d_in[5];
    const float* w10 = (const float*)d_in[6];
    const float* b10 = (const float*)d_in[7];
    const float* w20 = (const float*)d_in[8];
    const float* b20 = (const float*)d_in[9];
    const float* we1 = (const float*)d_in[10];
    const float* be1 = (const float*)d_in[11];
    const float* w11 = (const float*)d_in[12];
    const float* b11 = (const float*)d_in[13];
    const float* w21 = (const float*)d_in[14];
    const float* b21 = (const float*)d_in[15];
    const float* we2 = (const float*)d_in[16];
    const float* be2 = (const float*)d_in[17];
    const float* w12 = (const float*)d_in[18];
    const float* b12 = (const float*)d_in[19];
    const float* w22 = (const float*)d_in[20];
    const float* b22 = (const float*)d_in[21];
    const float* rw1 = (const float*)d_in[22];
    const float* rb1 = (const float*)d_in[23];
    const float* rw2 = (const float*)d_in[24];
    const float* rb2 = (const float*)d_in[25];

    const int N = in_sizes[0] / 16;
    const int E = in_sizes[2];
    const int M = 2 * N;

    float* HA = (float*)d_ws;                        // M*128 f32
    float* HB = HA + (size_t)M * 128;                // M*128 f32
    float* AG = HB + (size_t)M * 128;                // M*128 f32
    unsigned short* Hb = (unsigned short*)(AG + (size_t)M * 128);  // M*128 bf16
    unsigned short* Hhi = Hb + (size_t)M * 128;      // M*128 bf16 (hidden hi)
    unsigned short* Hlo = Hhi + (size_t)M * 128;     // M*128 bf16 (hidden lo)
    unsigned short* EABS = Hlo + (size_t)M * 128;    // E*16 bf16, CSR order
    int* deg = (int*)(EABS + (size_t)E * 16);        // N
    int* off = deg + N;                              // N+1
    int* pos = off + N + 1;                          // N
    int* bsum = pos + N;                             // 256
    int* csrsrc = bsum + 256;                        // E

    const int ntiles = (M + 31) / 32;
    const int eblocks = (E + 255) / 256;
    const int nblocks = (N + 255) / 256;
    const int mtiles = (M + 127) / 128;

    // ---- CSR build (once; shared by all 3 layers) ----
    hipMemsetAsync(deg, 0, (size_t)N * sizeof(int), stream);
    csr_count<<<eblocks, 256, 0, stream>>>(edst, deg, E);
    scan1<<<nblocks, 256, 0, stream>>>(deg, off, bsum, N);
    scan2<<<1, 256, 0, stream>>>(bsum, nblocks);
    scan3<<<nblocks, 256, 0, stream>>>(off, pos, bsum, deg, N);
    csr_fill<<<eblocks, 256, 0, stream>>>(esrc, edst, ea, pos, csrsrc,
                                          (uint4*)EABS, E);

    // H0 (M x 16), f32 + bf16
    init_h0<<<(N * 16 + 255) / 256, 256, 0, stream>>>(x, HA, Hb, N);

    // ---- layer 0 (din=16 -> 128), VALU path ----
    agg_gather16<<<(N + 7) / 8, 256, 0, stream>>>(csrsrc, off, (const uint4*)EABS,
                                                  we0, be0, Hb, AG, N);
    node_mlp<16, 128, true, true, true><<<ntiles, 256, 0, stream>>>(
        HA, AG, w10, b10, w20, b20, HB, Hb, M);

    // ---- layer 1 (128 -> 128), MFMA split MLP ----
    agg_gather128<<<(N + 3) / 4, 256, 0, stream>>>(csrsrc, off, EABS,
                                                   we1, be1, Hb, AG, N);
    mlp_a<<<mtiles, 256, 0, stream>>>(HB, AG, w11, b11, Hhi, Hlo, M);
    mlp_b<128, true, true><<<mtiles, 256, 0, stream>>>(Hhi, Hlo, w21, b21,
                                                       HA, Hb, M);

    // ---- layer 2 (128 -> 64), MFMA split MLP ----
    agg_gather128<<<(N + 3) / 4, 256, 0, stream>>>(csrsrc, off, EABS,
                                                   we2, be2, Hb, AG, N);
    mlp_a<<<mtiles, 256, 0, stream>>>(HA, AG, w12, b12, Hhi, Hlo, M);
    mlp_b<64, false, false><<<mtiles, 256, 0, stream>>>(Hhi, Hlo, w22, b22,
                                                        HB, nullptr, M);

    // ---- sign sum + readout (64 -> 128 -> 16), VALU path ----
    sum_signs<<<(N * 64 + 255) / 256, 256, 0, stream>>>(HB, AG, N);
    node_mlp<64, 16, false, false, false><<<(N + 31) / 32, 256, 0, stream>>>(
        AG, nullptr, rw1, rb1, rw2, rb2, (float*)d_out, nullptr, N);
}

// Round 14
// 947.918 us; speedup vs baseline: 1.1452x; 1.1452x over previous
//
#include <hip/hip_runtime.h>

// SignNet GINE: 3 layers, signs batched as 2N interleaved rows (2i=+x, 2i+1=-x).
// CSR gather aggregation (agg128 = proven r8/r12). VALU node MLPs (proven r5).
// Readout fused with sign-sum (SUM_PAIRS staging).
constexpr int DHID = 128;

typedef __attribute__((ext_vector_type(8))) short bf16x8v;
typedef __attribute__((ext_vector_type(4))) float f32x4v;

__device__ __forceinline__ float b2f(unsigned short u) {
    union { unsigned int i; float f; } v;
    v.i = ((unsigned int)u) << 16;
    return v.f;
}
__device__ __forceinline__ unsigned short f2b(float f) {
    union { float f; unsigned int i; } v;
    v.f = f;
    unsigned int x = v.i;
    return (unsigned short)((x + 0x7fff + ((x >> 16) & 1)) >> 16);
}
__device__ __forceinline__ unsigned int pack2(float a, float b) {
    return (unsigned int)f2b(a) | ((unsigned int)f2b(b) << 16);
}
__device__ __forceinline__ float bres(float w) { return w - b2f(f2b(w)); }
__device__ __forceinline__ void dot2b(float& acc, unsigned int a, unsigned int b) {
    asm("v_dot2_f32_bf16 %0, %1, %2, %0" : "+v"(acc) : "v"(a), "v"(b));
}

__global__ __launch_bounds__(256)
void init_h0(const float* __restrict__ x, float* __restrict__ H0,
             unsigned short* __restrict__ H0B, int n) {
    int i = blockIdx.x * 256 + threadIdx.x;   // over N*16
    if (i < n * 16) {
        int r = i >> 4, c = i & 15;
        float v = x[i];
        H0[(size_t)(2 * r) * 16 + c] = v;
        H0[(size_t)(2 * r + 1) * 16 + c] = -v;
        H0B[(size_t)(2 * r) * 16 + c] = f2b(v);
        H0B[(size_t)(2 * r + 1) * 16 + c] = f2b(-v);
    }
}

// ---------------- CSR build ----------------
__global__ __launch_bounds__(256)
void csr_count(const int* __restrict__ DST, int* __restrict__ deg, int E_) {
    int e = blockIdx.x * 256 + threadIdx.x;
    if (e < E_) atomicAdd(&deg[DST[e]], 1);
}

__global__ __launch_bounds__(256)
void scan1(const int* __restrict__ deg, int* __restrict__ off,
           int* __restrict__ bsum, int n) {
    __shared__ int s[256];
    int tid = threadIdx.x;
    int i = blockIdx.x * 256 + tid;
    int v = (i < n) ? deg[i] : 0;
    s[tid] = v;
    __syncthreads();
    for (int d = 1; d < 256; d <<= 1) {
        int t = (tid >= d) ? s[tid - d] : 0;
        __syncthreads();
        if (tid >= d) s[tid] += t;
        __syncthreads();
    }
    if (i < n) off[i] = s[tid] - v;
    if (tid == 255) bsum[blockIdx.x] = s[255];
}

__global__ __launch_bounds__(256)
void scan2(int* __restrict__ bsum, int nb) {
    __shared__ int s[256];
    int tid = threadIdx.x;
    int v = (tid < nb) ? bsum[tid] : 0;
    s[tid] = v;
    __syncthreads();
    for (int d = 1; d < 256; d <<= 1) {
        int t = (tid >= d) ? s[tid - d] : 0;
        __syncthreads();
        if (tid >= d) s[tid] += t;
        __syncthreads();
    }
    if (tid < nb) bsum[tid] = s[tid] - v;
}

__global__ __launch_bounds__(256)
void scan3(int* __restrict__ off, int* __restrict__ pos,
           const int* __restrict__ bsum, const int* __restrict__ deg, int n) {
    int i = blockIdx.x * 256 + threadIdx.x;
    if (i < n) {
        int o = off[i] + bsum[blockIdx.x];
        off[i] = o;
        pos[i] = o;
        if (i == n - 1) off[n] = o + deg[i];
    }
}

// Fill CSR: src index + edge attrs gathered into CSR order as bf16 (32B/edge).
__global__ __launch_bounds__(256)
void csr_fill(const int* __restrict__ SRC, const int* __restrict__ DST,
              const float* __restrict__ EA, int* __restrict__ pos,
              int* __restrict__ csrsrc, uint4* __restrict__ EABS, int E_) {
    int e = blockIdx.x * 256 + threadIdx.x;
    if (e < E_) {
        int d = DST[e];
        int j = atomicAdd(&pos[d], 1);
        csrsrc[j] = SRC[e];
        const float4* ea4 = (const float4*)(EA + (size_t)e * 16);
        float4 q0 = ea4[0], q1 = ea4[1], q2 = ea4[2], q3 = ea4[3];
        uint4 o0, o1;
        o0.x = pack2(q0.x, q0.y); o0.y = pack2(q0.z, q0.w);
        o0.z = pack2(q1.x, q1.y); o0.w = pack2(q1.z, q1.w);
        o1.x = pack2(q2.x, q2.y); o1.y = pack2(q2.z, q2.w);
        o1.z = pack2(q3.x, q3.y); o1.w = pack2(q3.z, q3.w);
        EABS[(size_t)2 * j] = o0;
        EABS[(size_t)2 * j + 1] = o1;
    }
}

// ---------------- gather aggregation (r12/r8 proven) ----------------
__global__ __launch_bounds__(256)
void agg_gather128(const int* __restrict__ CSRS, const int* __restrict__ OFF,
                   const unsigned short* __restrict__ EABS,
                   const float* __restrict__ WE, const float* __restrict__ BE,
                   const unsigned short* __restrict__ HB,
                   float* __restrict__ AGG, int n) {
    __shared__ float esm_all[4][16][132];
    const int tid = threadIdx.x;
    const int wv = tid >> 6;
    const int lane = tid & 63;
    const int node = blockIdx.x * 4 + wv;
    if (node >= n) return;
    float (*esm)[132] = esm_all[wv];

    const int col = lane & 15;
    const int grp = lane >> 4;          // 0..3
    const int klo = (grp & 1) * 8;

    bf16x8v bfrag[8];
#pragma unroll
    for (int cb = 0; cb < 8; ++cb) {
        bf16x8v b;
#pragma unroll
        for (int i = 0; i < 8; ++i) {
            float w = WE[(klo + i) * 128 + cb * 16 + col];
            unsigned short hi = f2b(w);
            unsigned short lo = f2b(bres(w));
            b[i] = (short)(grp >= 2 ? lo : hi);
        }
        bfrag[cb] = b;
    }
    float bias[8];
#pragma unroll
    for (int cb = 0; cb < 8; ++cb) bias[cb] = BE[cb * 16 + col];

    const int o = lane & 31;
    const int s = o >> 4;
    const int co = (o & 15) * 8;
    const int ep = lane >> 5;

    float acc[8];
#pragma unroll
    for (int i = 0; i < 8; ++i) acc[i] = 0.f;

    const int j0 = OFF[node], j1 = OFF[node + 1];
    const char* ebase = (const char*)EABS;

    for (int base = j0; base < j1; base += 16) {
        const int rem = j1 - base;
        uint4 a4 = *(const uint4*)(ebase + ((size_t)(base + col) << 5) +
                                   ((grp & 1) << 4));
        bf16x8v afrag = __builtin_bit_cast(bf16x8v, a4);
#pragma unroll
        for (int cb = 0; cb < 8; ++cb) {
            f32x4v c = {bias[cb], bias[cb], bias[cb], bias[cb]};
            f32x4v ev = __builtin_amdgcn_mfma_f32_16x16x32_bf16(afrag, bfrag[cb],
                                                                c, 0, 0, 0);
#pragma unroll
            for (int r = 0; r < 4; ++r) {
                const int slot = grp * 4 + r;
                esm[slot][cb * 16 + col] = (slot < rem) ? ev[r] : -1e30f;
            }
        }
        int srcs[8];
#pragma unroll
        for (int i = 0; i < 8; ++i) {
            const int eidx = base + 2 * i + ep;
            srcs[i] = CSRS[eidx < j1 ? eidx : (j1 - 1)];
        }
        uint4 hvv[8];
#pragma unroll
        for (int i = 0; i < 8; ++i)
            hvv[i] = *(const uint4*)(HB + (((size_t)(2 * srcs[i] + s)) << 7) + co);
#pragma unroll
        for (int i = 0; i < 8; ++i) {
            const uint4 hv = hvv[i];
            const float4* ep4 = (const float4*)&esm[2 * i + ep][co];
            float4 e0 = ep4[0], e1 = ep4[1];
            acc[0] += fmaxf(b2f(hv.x & 0xffff) + e0.x, 0.f);
            acc[1] += fmaxf(b2f(hv.x >> 16)    + e0.y, 0.f);
            acc[2] += fmaxf(b2f(hv.y & 0xffff) + e0.z, 0.f);
            acc[3] += fmaxf(b2f(hv.y >> 16)    + e0.w, 0.f);
            acc[4] += fmaxf(b2f(hv.z & 0xffff) + e1.x, 0.f);
            acc[5] += fmaxf(b2f(hv.z >> 16)    + e1.y, 0.f);
            acc[6] += fmaxf(b2f(hv.w & 0xffff) + e1.z, 0.f);
            acc[7] += fmaxf(b2f(hv.w >> 16)    + e1.w, 0.f);
        }
    }
#pragma unroll
    for (int i = 0; i < 8; ++i) acc[i] += __shfl_xor(acc[i], 32);
    if (lane < 32) {
        float* arow = AGG + (size_t)(2 * node + s) * 128 + co;
        float4 v0 = make_float4(acc[0], acc[1], acc[2], acc[3]);
        float4 v1 = make_float4(acc[4], acc[5], acc[6], acc[7]);
        ((float4*)arow)[0] = v0;
        ((float4*)arow)[1] = v1;
    }
}

// din=16: half-wave (32 lanes) per node.
__global__ __launch_bounds__(256)
void agg_gather16(const int* __restrict__ CSRS, const int* __restrict__ OFF,
                  const uint4* __restrict__ EABS, const float* __restrict__ WE,
                  const float* __restrict__ BE,
                  const unsigned short* __restrict__ HB,
                  float* __restrict__ AGG, int n) {
    const int l = threadIdx.x & 31;
    const int node = blockIdx.x * 8 + (threadIdx.x >> 5);
    if (node >= n) return;
    const int s = l >> 4;
    const int c = l & 15;
    unsigned int wh[8], wl[8];
#pragma unroll
    for (int t = 0; t < 8; ++t) {
        float a0 = WE[(2 * t) * 16 + c], a1 = WE[(2 * t + 1) * 16 + c];
        wh[t] = pack2(a0, a1);
        wl[t] = pack2(bres(a0), bres(a1));
    }
    const float bev = BE[c];
    float acc = 0.f;
    const int j0 = OFF[node], j1 = OFF[node + 1];
#pragma unroll 4
    for (int j = j0; j < j1; ++j) {
        int src = CSRS[j];
        uint4 p = EABS[(size_t)2 * j], q = EABS[(size_t)2 * j + 1];
        float ec = bev;
        dot2b(ec, p.x, wh[0]); dot2b(ec, p.y, wh[1]);
        dot2b(ec, p.z, wh[2]); dot2b(ec, p.w, wh[3]);
        dot2b(ec, q.x, wh[4]); dot2b(ec, q.y, wh[5]);
        dot2b(ec, q.z, wh[6]); dot2b(ec, q.w, wh[7]);
        dot2b(ec, p.x, wl[0]); dot2b(ec, p.y, wl[1]);
        dot2b(ec, p.z, wl[2]); dot2b(ec, p.w, wl[3]);
        dot2b(ec, q.x, wl[4]); dot2b(ec, q.y, wl[5]);
        dot2b(ec, q.z, wl[6]); dot2b(ec, q.w, wl[7]);
        float hv = b2f(HB[(size_t)(2 * src + s) * 16 + c]);
        acc += fmaxf(hv + ec, 0.f);
    }
    AGG[(size_t)(2 * node + s) * 16 + c] = acc;
}

// Fused node MLP (VALU, proven r5): OUT = maybe_relu(relu((X[+AGG])@W1+b1)@W2+b2)
// SUM_PAIRS: X has 2*rows rows (interleaved signs); staging sums rows 2r,2r+1.
template <int DIN, int DOUT, bool RELU_OUT, bool HAS_AGG, bool WRITE_B,
          bool SUM_PAIRS = false>
__global__ __launch_bounds__(256)
void node_mlp(const float* __restrict__ X, const float* __restrict__ AGG,
              const float* __restrict__ W1, const float* __restrict__ B1,
              const float* __restrict__ W2, const float* __restrict__ B2,
              float* __restrict__ OUT, unsigned short* __restrict__ OUTB,
              int rows) {
    __shared__ float sX[32 * DIN];
    __shared__ float sH[32 * DHID];
    const int tid = threadIdx.x;

    for (int row0 = blockIdx.x * 32; row0 < rows; row0 += gridDim.x * 32) {
        __syncthreads();
        constexpr int DIN4 = DIN / 4;
        for (int i = tid; i < 32 * DIN4; i += 256) {
            int r = i / DIN4, k4 = i % DIN4;
            int gr = row0 + r;
            float4 v = make_float4(0.f, 0.f, 0.f, 0.f);
            if (gr < rows) {
                if (SUM_PAIRS) {
                    float4 a = ((const float4*)X)[(size_t)(2 * gr) * DIN4 + k4];
                    float4 b = ((const float4*)X)[(size_t)(2 * gr + 1) * DIN4 + k4];
                    v.x = a.x + b.x; v.y = a.y + b.y;
                    v.z = a.z + b.z; v.w = a.w + b.w;
                } else {
                    v = ((const float4*)X)[(size_t)gr * DIN4 + k4];
                    if (HAS_AGG) {
                        float4 a = ((const float4*)AGG)[(size_t)gr * DIN4 + k4];
                        v.x += a.x; v.y += a.y; v.z += a.z; v.w += a.w;
                    }
                }
            }
            ((float4*)sX)[i] = v;
        }
        __syncthreads();
        {
            const int c = tid & 63;
            const int r0 = tid >> 6;
            float acc[8][2];
            const float b1a = B1[c], b1b = B1[c + 64];
#pragma unroll
            for (int j = 0; j < 8; ++j) {
                acc[j][0] = b1a;
                acc[j][1] = b1b;
            }
#pragma unroll 2
            for (int k4 = 0; k4 < DIN / 4; ++k4) {
                const int k = 4 * k4;
                float wa[4], wb[4];
#pragma unroll
                for (int kk = 0; kk < 4; ++kk) {
                    wa[kk] = W1[(k + kk) * DHID + c];
                    wb[kk] = W1[(k + kk) * DHID + c + 64];
                }
#pragma unroll
                for (int j = 0; j < 8; ++j) {
                    float4 xv = ((const float4*)sX)[((r0 + 4 * j) * DIN + k) >> 2];
                    acc[j][0] += xv.x * wa[0]; acc[j][1] += xv.x * wb[0];
                    acc[j][0] += xv.y * wa[1]; acc[j][1] += xv.y * wb[1];
                    acc[j][0] += xv.z * wa[2]; acc[j][1] += xv.z * wb[2];
                    acc[j][0] += xv.w * wa[3]; acc[j][1] += xv.w * wb[3];
                }
            }
#pragma unroll
            for (int j = 0; j < 8; ++j) {
                int r = r0 + 4 * j;
                sH[r * DHID + c] = fmaxf(acc[j][0], 0.f);
                sH[r * DHID + c + 64] = fmaxf(acc[j][1], 0.f);
            }
        }
        __syncthreads();
        {
            constexpr int HALF = DOUT / 2;
            constexpr int RP = 256 / HALF;
            constexpr int ITER = 32 / RP;
            const int c = tid % HALF;
            const int r0 = tid / HALF;
            float acc[ITER][2];
            const float bz0 = B2[c], bz1 = B2[c + HALF];
#pragma unroll
            for (int j = 0; j < ITER; ++j) {
                acc[j][0] = bz0;
                acc[j][1] = bz1;
            }
#pragma unroll 2
            for (int k4 = 0; k4 < DHID / 4; ++k4) {
                const int k = 4 * k4;
                float wa[4], wb[4];
#pragma unroll
                for (int kk = 0; kk < 4; ++kk) {
                    wa[kk] = W2[(k + kk) * DOUT + c];
                    wb[kk] = W2[(k + kk) * DOUT + c + HALF];
                }
#pragma unroll
                for (int j = 0; j < ITER; ++j) {
                    float4 hv = ((const float4*)sH)[((r0 + RP * j) * DHID + k) >> 2];
                    acc[j][0] += hv.x * wa[0]; acc[j][1] += hv.x * wb[0];
                    acc[j][0] += hv.y * wa[1]; acc[j][1] += hv.y * wb[1];
                    acc[j][0] += hv.z * wa[2]; acc[j][1] += hv.z * wb[2];
                    acc[j][0] += hv.w * wa[3]; acc[j][1] += hv.w * wb[3];
                }
            }
#pragma unroll
            for (int j = 0; j < ITER; ++j) {
                int gr = row0 + r0 + RP * j;
                if (gr < rows) {
                    float o0 = acc[j][0], o1 = acc[j][1];
                    if (RELU_OUT) {
                        o0 = fmaxf(o0, 0.f);
                        o1 = fmaxf(o1, 0.f);
                    }
                    OUT[(size_t)gr * DOUT + c] = o0;
                    OUT[(size_t)gr * DOUT + c + HALF] = o1;
                    if (WRITE_B) {
                        OUTB[(size_t)gr * DOUT + c] = f2b(o0);
                        OUTB[(size_t)gr * DOUT + c + HALF] = f2b(o1);
                    }
                }
            }
        }
    }
}

extern "C" void kernel_launch(void* const* d_in, const int* in_sizes, int n_in,
                              void* d_out, int out_size, void* d_ws, size_t ws_size,
                              hipStream_t stream) {
    const float* x = (const float*)d_in[0];
    const float* ea = (const float*)d_in[1];
    const int* esrc = (const int*)d_in[2];
    const int* edst = (const int*)d_in[3];
    const float* we0 = (const float*)d_in[4];
    const float* be0 = (const float*)d_in[5];
    const float* w10 = (const float*)d_in[6];
    const float* b10 = (const float*)d_in[7];
    const float* w20 = (const float*)d_in[8];
    const float* b20 = (const float*)d_in[9];
    const float* we1 = (const float*)d_in[10];
    const float* be1 = (const float*)d_in[11];
    const float* w11 = (const float*)d_in[12];
    const float* b11 = (const float*)d_in[13];
    const float* w21 = (const float*)d_in[14];
    const float* b21 = (const float*)d_in[15];
    const float* we2 = (const float*)d_in[16];
    const float* be2 = (const float*)d_in[17];
    const float* w12 = (const float*)d_in[18];
    const float* b12 = (const float*)d_in[19];
    const float* w22 = (const float*)d_in[20];
    const float* b22 = (const float*)d_in[21];
    const float* rw1 = (const float*)d_in[22];
    const float* rb1 = (const float*)d_in[23];
    const float* rw2 = (const float*)d_in[24];
    const float* rb2 = (const float*)d_in[25];

    const int N = in_sizes[0] / 16;
    const int E = in_sizes[2];
    const int M = 2 * N;

    float* HA = (float*)d_ws;                        // M*128 f32
    float* HB = HA + (size_t)M * 128;                // M*128 f32
    float* AG = HB + (size_t)M * 128;                // M*128 f32
    unsigned short* Hb = (unsigned short*)(AG + (size_t)M * 128);  // M*128 bf16
    unsigned short* EABS = Hb + (size_t)M * 128;     // E*16 bf16, CSR order
    int* deg = (int*)(EABS + (size_t)E * 16);        // N
    int* off = deg + N;                              // N+1
    int* pos = off + N + 1;                          // N
    int* bsum = pos + N;                             // 256
    int* csrsrc = bsum + 256;                        // E

    const int ntiles = (M + 31) / 32;
    const int eblocks = (E + 255) / 256;
    const int nblocks = (N + 255) / 256;

    // ---- CSR build (once; shared by all 3 layers) ----
    hipMemsetAsync(deg, 0, (size_t)N * sizeof(int), stream);
    csr_count<<<eblocks, 256, 0, stream>>>(edst, deg, E);
    scan1<<<nblocks, 256, 0, stream>>>(deg, off, bsum, N);
    scan2<<<1, 256, 0, stream>>>(bsum, nblocks);
    scan3<<<nblocks, 256, 0, stream>>>(off, pos, bsum, deg, N);
    csr_fill<<<eblocks, 256, 0, stream>>>(esrc, edst, ea, pos, csrsrc,
                                          (uint4*)EABS, E);

    // H0 (M x 16), f32 + bf16
    init_h0<<<(N * 16 + 255) / 256, 256, 0, stream>>>(x, HA, Hb, N);

    // ---- layer 0 (din=16 -> 128) ----
    agg_gather16<<<(N + 7) / 8, 256, 0, stream>>>(csrsrc, off, (const uint4*)EABS,
                                                  we0, be0, Hb, AG, N);
    node_mlp<16, 128, true, true, true><<<ntiles, 256, 0, stream>>>(
        HA, AG, w10, b10, w20, b20, HB, Hb, M);

    // ---- layer 1 (128 -> 128) ----
    agg_gather128<<<(N + 3) / 4, 256, 0, stream>>>(csrsrc, off, EABS,
                                                   we1, be1, Hb, AG, N);
    node_mlp<128, 128, true, true, true><<<ntiles, 256, 0, stream>>>(
        HB, AG, w11, b11, w21, b21, HA, Hb, M);

    // ---- layer 2 (128 -> 64) ----
    agg_gather128<<<(N + 3) / 4, 256, 0, stream>>>(csrsrc, off, EABS,
                                                   we2, be2, Hb, AG, N);
    node_mlp<128, 64, false, true, false><<<ntiles, 256, 0, stream>>>(
        HA, AG, w12, b12, w22, b22, HB, nullptr, M);

    // ---- fused sign-sum + readout (64 -> 128 -> 16) ----
    node_mlp<64, 16, false, false, false, true><<<(N + 31) / 32, 256, 0, stream>>>(
        HB, nullptr, rw1, rb1, rw2, rb2, (float*)d_out, nullptr, N);
}

// Round 15
// 943.959 us; speedup vs baseline: 1.1500x; 1.0042x over previous
//
#include <hip/hip_runtime.h>

// SignNet GINE: 3 layers, signs batched as 2N interleaved rows (2i=+x, 2i+1=-x).
// CSR gather aggregation (agg128 = proven r8/r12). VALU node MLPs (r5) with
// PACKED float4 weight loads (pack_weights: W[KxC] -> [k/4][c][4]).
// Readout fused with sign-sum (SUM_PAIRS staging).
constexpr int DHID = 128;

typedef __attribute__((ext_vector_type(8))) short bf16x8v;
typedef __attribute__((ext_vector_type(4))) float f32x4v;

__device__ __forceinline__ float b2f(unsigned short u) {
    union { unsigned int i; float f; } v;
    v.i = ((unsigned int)u) << 16;
    return v.f;
}
__device__ __forceinline__ unsigned short f2b(float f) {
    union { float f; unsigned int i; } v;
    v.f = f;
    unsigned int x = v.i;
    return (unsigned short)((x + 0x7fff + ((x >> 16) & 1)) >> 16);
}
__device__ __forceinline__ unsigned int pack2(float a, float b) {
    return (unsigned int)f2b(a) | ((unsigned int)f2b(b) << 16);
}
__device__ __forceinline__ float bres(float w) { return w - b2f(f2b(w)); }
__device__ __forceinline__ void dot2b(float& acc, unsigned int a, unsigned int b) {
    asm("v_dot2_f32_bf16 %0, %1, %2, %0" : "+v"(acc) : "v"(a), "v"(b));
}

__global__ __launch_bounds__(256)
void init_h0(const float* __restrict__ x, float* __restrict__ H0,
             unsigned short* __restrict__ H0B, int n) {
    int i = blockIdx.x * 256 + threadIdx.x;   // over N*16
    if (i < n * 16) {
        int r = i >> 4, c = i & 15;
        float v = x[i];
        H0[(size_t)(2 * r) * 16 + c] = v;
        H0[(size_t)(2 * r + 1) * 16 + c] = -v;
        H0B[(size_t)(2 * r) * 16 + c] = f2b(v);
        H0B[(size_t)(2 * r + 1) * 16 + c] = f2b(-v);
    }
}

// Pack all weight matrices W[KxC] -> P[base + (k/4*C + c)*4 + k%4].
// Segments (floats): w10@0(2048) w20@2048(16384) w11@18432(16384)
// w21@34816(16384) w12@51200(16384) w22@67584(8192) rw1@75776(8192)
// rw2@83968(2048); total 86016.
__global__ __launch_bounds__(256)
void pack_weights(const float* __restrict__ w10, const float* __restrict__ w20,
                  const float* __restrict__ w11, const float* __restrict__ w21,
                  const float* __restrict__ w12, const float* __restrict__ w22,
                  const float* __restrict__ rw1, const float* __restrict__ rw2,
                  float* __restrict__ P) {
    int i = blockIdx.x * 256 + threadIdx.x;
    const float* src; int C, base, off;
    if (i < 2048)       { src = w10; C = 128; base = 0;     off = i; }
    else if (i < 18432) { src = w20; C = 128; base = 2048;  off = i - 2048; }
    else if (i < 34816) { src = w11; C = 128; base = 18432; off = i - 18432; }
    else if (i < 51200) { src = w21; C = 128; base = 34816; off = i - 34816; }
    else if (i < 67584) { src = w12; C = 128; base = 51200; off = i - 51200; }
    else if (i < 75776) { src = w22; C = 64;  base = 67584; off = i - 67584; }
    else if (i < 83968) { src = rw1; C = 128; base = 75776; off = i - 75776; }
    else if (i < 86016) { src = rw2; C = 16;  base = 83968; off = i - 83968; }
    else return;
    int k = off / C, c = off % C;
    P[base + (size_t)((k >> 2) * C + c) * 4 + (k & 3)] = src[off];
}

// ---------------- CSR build ----------------
__global__ __launch_bounds__(256)
void csr_count(const int* __restrict__ DST, int* __restrict__ deg, int E_) {
    int e = blockIdx.x * 256 + threadIdx.x;
    if (e < E_) atomicAdd(&deg[DST[e]], 1);
}

__global__ __launch_bounds__(256)
void scan1(const int* __restrict__ deg, int* __restrict__ off,
           int* __restrict__ bsum, int n) {
    __shared__ int s[256];
    int tid = threadIdx.x;
    int i = blockIdx.x * 256 + tid;
    int v = (i < n) ? deg[i] : 0;
    s[tid] = v;
    __syncthreads();
    for (int d = 1; d < 256; d <<= 1) {
        int t = (tid >= d) ? s[tid - d] : 0;
        __syncthreads();
        if (tid >= d) s[tid] += t;
        __syncthreads();
    }
    if (i < n) off[i] = s[tid] - v;
    if (tid == 255) bsum[blockIdx.x] = s[255];
}

__global__ __launch_bounds__(256)
void scan2(int* __restrict__ bsum, int nb) {
    __shared__ int s[256];
    int tid = threadIdx.x;
    int v = (tid < nb) ? bsum[tid] : 0;
    s[tid] = v;
    __syncthreads();
    for (int d = 1; d < 256; d <<= 1) {
        int t = (tid >= d) ? s[tid - d] : 0;
        __syncthreads();
        if (tid >= d) s[tid] += t;
        __syncthreads();
    }
    if (tid < nb) bsum[tid] = s[tid] - v;
}

__global__ __launch_bounds__(256)
void scan3(int* __restrict__ off, int* __restrict__ pos,
           const int* __restrict__ bsum, const int* __restrict__ deg, int n) {
    int i = blockIdx.x * 256 + threadIdx.x;
    if (i < n) {
        int o = off[i] + bsum[blockIdx.x];
        off[i] = o;
        pos[i] = o;
        if (i == n - 1) off[n] = o + deg[i];
    }
}

// Fill CSR: src index + edge attrs gathered into CSR order as bf16 (32B/edge).
__global__ __launch_bounds__(256)
void csr_fill(const int* __restrict__ SRC, const int* __restrict__ DST,
              const float* __restrict__ EA, int* __restrict__ pos,
              int* __restrict__ csrsrc, uint4* __restrict__ EABS, int E_) {
    int e = blockIdx.x * 256 + threadIdx.x;
    if (e < E_) {
        int d = DST[e];
        int j = atomicAdd(&pos[d], 1);
        csrsrc[j] = SRC[e];
        const float4* ea4 = (const float4*)(EA + (size_t)e * 16);
        float4 q0 = ea4[0], q1 = ea4[1], q2 = ea4[2], q3 = ea4[3];
        uint4 o0, o1;
        o0.x = pack2(q0.x, q0.y); o0.y = pack2(q0.z, q0.w);
        o0.z = pack2(q1.x, q1.y); o0.w = pack2(q1.z, q1.w);
        o1.x = pack2(q2.x, q2.y); o1.y = pack2(q2.z, q2.w);
        o1.z = pack2(q3.x, q3.y); o1.w = pack2(q3.z, q3.w);
        EABS[(size_t)2 * j] = o0;
        EABS[(size_t)2 * j + 1] = o1;
    }
}

// ---------------- gather aggregation (r12/r8 proven) ----------------
__global__ __launch_bounds__(256)
void agg_gather128(const int* __restrict__ CSRS, const int* __restrict__ OFF,
                   const unsigned short* __restrict__ EABS,
                   const float* __restrict__ WE, const float* __restrict__ BE,
                   const unsigned short* __restrict__ HB,
                   float* __restrict__ AGG, int n) {
    __shared__ float esm_all[4][16][132];
    const int tid = threadIdx.x;
    const int wv = tid >> 6;
    const int lane = tid & 63;
    const int node = blockIdx.x * 4 + wv;
    if (node >= n) return;
    float (*esm)[132] = esm_all[wv];

    const int col = lane & 15;
    const int grp = lane >> 4;          // 0..3
    const int klo = (grp & 1) * 8;

    bf16x8v bfrag[8];
#pragma unroll
    for (int cb = 0; cb < 8; ++cb) {
        bf16x8v b;
#pragma unroll
        for (int i = 0; i < 8; ++i) {
            float w = WE[(klo + i) * 128 + cb * 16 + col];
            unsigned short hi = f2b(w);
            unsigned short lo = f2b(bres(w));
            b[i] = (short)(grp >= 2 ? lo : hi);
        }
        bfrag[cb] = b;
    }
    float bias[8];
#pragma unroll
    for (int cb = 0; cb < 8; ++cb) bias[cb] = BE[cb * 16 + col];

    const int o = lane & 31;
    const int s = o >> 4;
    const int co = (o & 15) * 8;
    const int ep = lane >> 5;

    float acc[8];
#pragma unroll
    for (int i = 0; i < 8; ++i) acc[i] = 0.f;

    const int j0 = OFF[node], j1 = OFF[node + 1];
    const char* ebase = (const char*)EABS;

    for (int base = j0; base < j1; base += 16) {
        const int rem = j1 - base;
        uint4 a4 = *(const uint4*)(ebase + ((size_t)(base + col) << 5) +
                                   ((grp & 1) << 4));
        bf16x8v afrag = __builtin_bit_cast(bf16x8v, a4);
#pragma unroll
        for (int cb = 0; cb < 8; ++cb) {
            f32x4v c = {bias[cb], bias[cb], bias[cb], bias[cb]};
            f32x4v ev = __builtin_amdgcn_mfma_f32_16x16x32_bf16(afrag, bfrag[cb],
                                                                c, 0, 0, 0);
#pragma unroll
            for (int r = 0; r < 4; ++r) {
                const int slot = grp * 4 + r;
                esm[slot][cb * 16 + col] = (slot < rem) ? ev[r] : -1e30f;
            }
        }
        int srcs[8];
#pragma unroll
        for (int i = 0; i < 8; ++i) {
            const int eidx = base + 2 * i + ep;
            srcs[i] = CSRS[eidx < j1 ? eidx : (j1 - 1)];
        }
        uint4 hvv[8];
#pragma unroll
        for (int i = 0; i < 8; ++i)
            hvv[i] = *(const uint4*)(HB + (((size_t)(2 * srcs[i] + s)) << 7) + co);
#pragma unroll
        for (int i = 0; i < 8; ++i) {
            const uint4 hv = hvv[i];
            const float4* ep4 = (const float4*)&esm[2 * i + ep][co];
            float4 e0 = ep4[0], e1 = ep4[1];
            acc[0] += fmaxf(b2f(hv.x & 0xffff) + e0.x, 0.f);
            acc[1] += fmaxf(b2f(hv.x >> 16)    + e0.y, 0.f);
            acc[2] += fmaxf(b2f(hv.y & 0xffff) + e0.z, 0.f);
            acc[3] += fmaxf(b2f(hv.y >> 16)    + e0.w, 0.f);
            acc[4] += fmaxf(b2f(hv.z & 0xffff) + e1.x, 0.f);
            acc[5] += fmaxf(b2f(hv.z >> 16)    + e1.y, 0.f);
            acc[6] += fmaxf(b2f(hv.w & 0xffff) + e1.z, 0.f);
            acc[7] += fmaxf(b2f(hv.w >> 16)    + e1.w, 0.f);
        }
    }
#pragma unroll
    for (int i = 0; i < 8; ++i) acc[i] += __shfl_xor(acc[i], 32);
    if (lane < 32) {
        float* arow = AGG + (size_t)(2 * node + s) * 128 + co;
        float4 v0 = make_float4(acc[0], acc[1], acc[2], acc[3]);
        float4 v1 = make_float4(acc[4], acc[5], acc[6], acc[7]);
        ((float4*)arow)[0] = v0;
        ((float4*)arow)[1] = v1;
    }
}

// din=16: half-wave (32 lanes) per node.
__global__ __launch_bounds__(256)
void agg_gather16(const int* __restrict__ CSRS, const int* __restrict__ OFF,
                  const uint4* __restrict__ EABS, const float* __restrict__ WE,
                  const float* __restrict__ BE,
                  const unsigned short* __restrict__ HB,
                  float* __restrict__ AGG, int n) {
    const int l = threadIdx.x & 31;
    const int node = blockIdx.x * 8 + (threadIdx.x >> 5);
    if (node >= n) return;
    const int s = l >> 4;
    const int c = l & 15;
    unsigned int wh[8], wl[8];
#pragma unroll
    for (int t = 0; t < 8; ++t) {
        float a0 = WE[(2 * t) * 16 + c], a1 = WE[(2 * t + 1) * 16 + c];
        wh[t] = pack2(a0, a1);
        wl[t] = pack2(bres(a0), bres(a1));
    }
    const float bev = BE[c];
    float acc = 0.f;
    const int j0 = OFF[node], j1 = OFF[node + 1];
#pragma unroll 4
    for (int j = j0; j < j1; ++j) {
        int src = CSRS[j];
        uint4 p = EABS[(size_t)2 * j], q = EABS[(size_t)2 * j + 1];
        float ec = bev;
        dot2b(ec, p.x, wh[0]); dot2b(ec, p.y, wh[1]);
        dot2b(ec, p.z, wh[2]); dot2b(ec, p.w, wh[3]);
        dot2b(ec, q.x, wh[4]); dot2b(ec, q.y, wh[5]);
        dot2b(ec, q.z, wh[6]); dot2b(ec, q.w, wh[7]);
        dot2b(ec, p.x, wl[0]); dot2b(ec, p.y, wl[1]);
        dot2b(ec, p.z, wl[2]); dot2b(ec, p.w, wl[3]);
        dot2b(ec, q.x, wl[4]); dot2b(ec, q.y, wl[5]);
        dot2b(ec, q.z, wl[6]); dot2b(ec, q.w, wl[7]);
        float hv = b2f(HB[(size_t)(2 * src + s) * 16 + c]);
        acc += fmaxf(hv + ec, 0.f);
    }
    AGG[(size_t)(2 * node + s) * 16 + c] = acc;
}

// Fused node MLP (VALU, r5 structure) with PACKED float4 weights.
// W1p/W2p layout: float4[K/4][C] (kk contiguous per (k4,c)).
// SUM_PAIRS: X has 2*rows rows (interleaved signs); staging sums rows 2r,2r+1.
template <int DIN, int DOUT, bool RELU_OUT, bool HAS_AGG, bool WRITE_B,
          bool SUM_PAIRS = false>
__global__ __launch_bounds__(256)
void node_mlp(const float* __restrict__ X, const float* __restrict__ AGG,
              const float* __restrict__ W1p, const float* __restrict__ B1,
              const float* __restrict__ W2p, const float* __restrict__ B2,
              float* __restrict__ OUT, unsigned short* __restrict__ OUTB,
              int rows) {
    __shared__ float sX[32 * DIN];
    __shared__ float sH[32 * DHID];
    const int tid = threadIdx.x;

    for (int row0 = blockIdx.x * 32; row0 < rows; row0 += gridDim.x * 32) {
        __syncthreads();
        constexpr int DIN4 = DIN / 4;
        for (int i = tid; i < 32 * DIN4; i += 256) {
            int r = i / DIN4, k4 = i % DIN4;
            int gr = row0 + r;
            float4 v = make_float4(0.f, 0.f, 0.f, 0.f);
            if (gr < rows) {
                if (SUM_PAIRS) {
                    float4 a = ((const float4*)X)[(size_t)(2 * gr) * DIN4 + k4];
                    float4 b = ((const float4*)X)[(size_t)(2 * gr + 1) * DIN4 + k4];
                    v.x = a.x + b.x; v.y = a.y + b.y;
                    v.z = a.z + b.z; v.w = a.w + b.w;
                } else {
                    v = ((const float4*)X)[(size_t)gr * DIN4 + k4];
                    if (HAS_AGG) {
                        float4 a = ((const float4*)AGG)[(size_t)gr * DIN4 + k4];
                        v.x += a.x; v.y += a.y; v.z += a.z; v.w += a.w;
                    }
                }
            }
            ((float4*)sX)[i] = v;
        }
        __syncthreads();
        {
            const int c = tid & 63;
            const int r0 = tid >> 6;
            float acc[8][2];
            const float b1a = B1[c], b1b = B1[c + 64];
#pragma unroll
            for (int j = 0; j < 8; ++j) {
                acc[j][0] = b1a;
                acc[j][1] = b1b;
            }
#pragma unroll 2
            for (int k4 = 0; k4 < DIN / 4; ++k4) {
                float4 wa = ((const float4*)W1p)[k4 * DHID + c];
                float4 wb = ((const float4*)W1p)[k4 * DHID + c + 64];
#pragma unroll
                for (int j = 0; j < 8; ++j) {
                    float4 xv = ((const float4*)sX)[((r0 + 4 * j) * DIN) / 4 + k4];
                    acc[j][0] += xv.x * wa.x; acc[j][1] += xv.x * wb.x;
                    acc[j][0] += xv.y * wa.y; acc[j][1] += xv.y * wb.y;
                    acc[j][0] += xv.z * wa.z; acc[j][1] += xv.z * wb.z;
                    acc[j][0] += xv.w * wa.w; acc[j][1] += xv.w * wb.w;
                }
            }
#pragma unroll
            for (int j = 0; j < 8; ++j) {
                int r = r0 + 4 * j;
                sH[r * DHID + c] = fmaxf(acc[j][0], 0.f);
                sH[r * DHID + c + 64] = fmaxf(acc[j][1], 0.f);
            }
        }
        __syncthreads();
        {
            constexpr int HALF = DOUT / 2;
            constexpr int RP = 256 / HALF;
            constexpr int ITER = 32 / RP;
            const int c = tid % HALF;
            const int r0 = tid / HALF;
            float acc[ITER][2];
            const float bz0 = B2[c], bz1 = B2[c + HALF];
#pragma unroll
            for (int j = 0; j < ITER; ++j) {
                acc[j][0] = bz0;
                acc[j][1] = bz1;
            }
#pragma unroll 2
            for (int k4 = 0; k4 < DHID / 4; ++k4) {
                float4 wa = ((const float4*)W2p)[k4 * DOUT + c];
                float4 wb = ((const float4*)W2p)[k4 * DOUT + c + HALF];
#pragma unroll
                for (int j = 0; j < ITER; ++j) {
                    float4 hv = ((const float4*)sH)[((r0 + RP * j) * DHID) / 4 + k4];
                    acc[j][0] += hv.x * wa.x; acc[j][1] += hv.x * wb.x;
                    acc[j][0] += hv.y * wa.y; acc[j][1] += hv.y * wb.y;
                    acc[j][0] += hv.z * wa.z; acc[j][1] += hv.z * wb.z;
                    acc[j][0] += hv.w * wa.w; acc[j][1] += hv.w * wb.w;
                }
            }
#pragma unroll
            for (int j = 0; j < ITER; ++j) {
                int gr = row0 + r0 + RP * j;
                if (gr < rows) {
                    float o0 = acc[j][0], o1 = acc[j][1];
                    if (RELU_OUT) {
                        o0 = fmaxf(o0, 0.f);
                        o1 = fmaxf(o1, 0.f);
                    }
                    OUT[(size_t)gr * DOUT + c] = o0;
                    OUT[(size_t)gr * DOUT + c + HALF] = o1;
                    if (WRITE_B) {
                        OUTB[(size_t)gr * DOUT + c] = f2b(o0);
                        OUTB[(size_t)gr * DOUT + c + HALF] = f2b(o1);
                    }
                }
            }
        }
    }
}

extern "C" void kernel_launch(void* const* d_in, const int* in_sizes, int n_in,
                              void* d_out, int out_size, void* d_ws, size_t ws_size,
                              hipStream_t stream) {
    const float* x = (const float*)d_in[0];
    const float* ea = (const float*)d_in[1];
    const int* esrc = (const int*)d_in[2];
    const int* edst = (const int*)d_in[3];
    const float* we0 = (const float*)d_in[4];
    const float* be0 = (const float*)d_in[5];
    const float* w10 = (const float*)d_in[6];
    const float* b10 = (const float*)d_in[7];
    const float* w20 = (const float*)d_in[8];
    const float* b20 = (const float*)d_in[9];
    const float* we1 = (const float*)d_in[10];
    const float* be1 = (const float*)d_in[11];
    const float* w11 = (const float*)d_in[12];
    const float* b11 = (const float*)d_in[13];
    const float* w21 = (const float*)d_in[14];
    const float* b21 = (const float*)d_in[15];
    const float* we2 = (const float*)d_in[16];
    const float* be2 = (const float*)d_in[17];
    const float* w12 = (const float*)d_in[18];
    const float* b12 = (const float*)d_in[19];
    const float* w22 = (const float*)d_in[20];
    const float* b22 = (const float*)d_in[21];
    const float* rw1 = (const float*)d_in[22];
    const float* rb1 = (const float*)d_in[23];
    const float* rw2 = (const float*)d_in[24];
    const float* rb2 = (const float*)d_in[25];

    const int N = in_sizes[0] / 16;
    const int E = in_sizes[2];
    const int M = 2 * N;

    float* HA = (float*)d_ws;                        // M*128 f32
    float* HB = HA + (size_t)M * 128;                // M*128 f32
    float* AG = HB + (size_t)M * 128;                // M*128 f32
    unsigned short* Hb = (unsigned short*)(AG + (size_t)M * 128);  // M*128 bf16
    unsigned short* EABS = Hb + (size_t)M * 128;     // E*16 bf16, CSR order
    int* deg = (int*)(EABS + (size_t)E * 16);        // N
    int* off = deg + N;                              // N+1
    int* pos = off + N + 1;                          // N
    int* bsum = pos + N;                             // 256
    int* csrsrc = bsum + 256;                        // E
    float* Wp = (float*)(csrsrc + E);                // 86016 packed weights

    const int ntiles = (M + 31) / 32;
    const int eblocks = (E + 255) / 256;
    const int nblocks = (N + 255) / 256;

    // ---- CSR build (once; shared by all 3 layers) + weight packing ----
    hipMemsetAsync(deg, 0, (size_t)N * sizeof(int), stream);
    csr_count<<<eblocks, 256, 0, stream>>>(edst, deg, E);
    scan1<<<nblocks, 256, 0, stream>>>(deg, off, bsum, N);
    scan2<<<1, 256, 0, stream>>>(bsum, nblocks);
    scan3<<<nblocks, 256, 0, stream>>>(off, pos, bsum, deg, N);
    csr_fill<<<eblocks, 256, 0, stream>>>(esrc, edst, ea, pos, csrsrc,
                                          (uint4*)EABS, E);
    pack_weights<<<(86016 + 255) / 256, 256, 0, stream>>>(
        w10, w20, w11, w21, w12, w22, rw1, rw2, Wp);

    // H0 (M x 16), f32 + bf16
    init_h0<<<(N * 16 + 255) / 256, 256, 0, stream>>>(x, HA, Hb, N);

    // ---- layer 0 (din=16 -> 128) ----
    agg_gather16<<<(N + 7) / 8, 256, 0, stream>>>(csrsrc, off, (const uint4*)EABS,
                                                  we0, be0, Hb, AG, N);
    node_mlp<16, 128, true, true, true><<<ntiles, 256, 0, stream>>>(
        HA, AG, Wp + 0, b10, Wp + 2048, b20, HB, Hb, M);

    // ---- layer 1 (128 -> 128) ----
    agg_gather128<<<(N + 3) / 4, 256, 0, stream>>>(csrsrc, off, EABS,
                                                   we1, be1, Hb, AG, N);
    node_mlp<128, 128, true, true, true><<<ntiles, 256, 0, stream>>>(
        HB, AG, Wp + 18432, b11, Wp + 34816, b21, HA, Hb, M);

    // ---- layer 2 (128 -> 64) ----
    agg_gather128<<<(N + 3) / 4, 256, 0, stream>>>(csrsrc, off, EABS,
                                                   we2, be2, Hb, AG, N);
    node_mlp<128, 64, false, true, false><<<ntiles, 256, 0, stream>>>(
        HA, AG, Wp + 51200, b12, Wp + 67584, b22, HB, nullptr, M);

    // ---- fused sign-sum + readout (64 -> 128 -> 16) ----
    node_mlp<64, 16, false, false, false, true><<<(N + 31) / 32, 256, 0, stream>>>(
        HB, nullptr, Wp + 75776, rb1, Wp + 83968, rb2, (float*)d_out, nullptr, N);
}